// Round 20
// baseline (242.838 us; speedup 1.0000x reference)
//
#include <hip/hip_runtime.h>

#define DD 64
#define HH 256
#define WW 256
#define NN (DD*HH*WW)   // 4194304
#define GHS 2048        // stats-hash slots per copy (power of 2; >= 2x ref L_MAX)
#define NCOPY 16        // replicated stats hashes (contention spread)
#define PHS 131072      // global pair-hash slots (power of 2, 64-bit keys)
#define NSEG (NN/32)    // 131072 bitmask words

// tile for local CCL phase
#define TZ 8
#define TY 32
#define TX 32
#define TVOX (TZ*TY*TX) // 8192 -> 32 KB LDS

// face-voxel enumeration for cross-tile pass
#define CA 458752            // 7 * 65536   (z-faces)
#define CB 114688            // 7 * 16384   (each of y0/y31/x0/x31 faces)
#define CFACE (CA + 4*CB)    // 917504 = 3584 * 256

// ---------------- union-find (works on LDS or global) ----------------
// Safety: every write stores an ancestor and preserves P[x] <= x; 4B accesses
// are HW-atomic, so concurrent halving stores cannot lose connectivity.
__device__ __forceinline__ int ufind(int* P, int x){
  int p = P[x];
  while (p != x){
    int gp = P[p];
    if (gp != p) P[x] = gp;   // path halving
    x = gp;
    p = P[x];
  }
  return x;
}

__device__ __forceinline__ int ufind_ro(const int* P, int x){
  int p = P[x];
  while (p != x){ x = p; p = P[x]; }
  return x;
}

__device__ __forceinline__ void uunion(int* P, int a, int b){
  while (true){
    a = ufind(P, a);
    b = ufind(P, b);
    if (a == b) return;
    if (a < b){ int t = a; a = b; b = t; }   // link big -> small
    int old = atomicMin(&P[a], b);
    if (old == a) return;
    a = old;
  }
}

// run start of bit x in mask m (bit x must be set)
__device__ __forceinline__ int run_start(unsigned m, int x){
  unsigned zb = (~m) & ((x == 0) ? 0u : ((1u << x) - 1u));
  return (zb == 0) ? 0 : (32 - __builtin_clz(zb));
}

__device__ __forceinline__ int refl(int v, int L){ return v < 0 ? 1 : (v >= L ? L - 2 : v); }

// ---------------- phase A: run-granular tile-local CCL, worklist-balanced ----------------
__global__ __launch_bounds__(1024) void k_local(const float* __restrict__ in,
                                                int* __restrict__ parent,
                                                unsigned* __restrict__ fgbits,
                                                int* __restrict__ hkey,
                                                int* __restrict__ harea,
                                                int* __restrict__ hper,
                                                unsigned long long* __restrict__ ph){
  __shared__ int sl[TVOX];                // union-find nodes: run-start entries only
  __shared__ unsigned srow[256];          // fg mask per (lz,ly) row
  __shared__ int q[4096];                 // run-start worklist (max 16 runs/row * 256)
  __shared__ int qn;
  const int t = threadIdx.x;
  const int lane = t & 63;
  const int b = blockIdx.x;               // 512 tiles: 8 x 8 x 8
  const int z0 = (b >> 6) * TZ;
  const int y0 = ((b >> 3) & 7) * TY;
  const int x0 = (b & 7) * TX;

  // init NCOPY stats-hash copies (16*2048 = 32768 = 32 blocks x 1024)
  if (b < (NCOPY * GHS) / 1024){ int j = b * 1024 + t; hkey[j] = -1; harea[j] = 0; hper[j] = 0; }
  { int j = b * 1024 + t; if (j < PHS) ph[j] = ~0ULL; }   // pair hash sentinel
  if (t == 0) qn = 0;

  // blocked mapping: thread t owns one byte (8 voxels) of row (t>>2)
  const int row = t >> 2;                 // (lz<<5)|ly
  const int xb  = (t & 3) * 8;
  const int lz  = row >> 5, ly = row & 31;
  const int gi0 = ((z0 + lz) << 16) | ((y0 + ly) << 8) | (x0 + xb);

  // A1: vectorized load -> fg byte -> row mask via 2 shuffle rounds
  float4 f0 = *(const float4*)(in + gi0);
  float4 f1 = *(const float4*)(in + gi0 + 4);
  int by = (f0.x > 0.5f)        | ((f0.y > 0.5f) << 1) |
           ((f0.z > 0.5f) << 2) | ((f0.w > 0.5f) << 3) |
           ((f1.x > 0.5f) << 4) | ((f1.y > 0.5f) << 5) |
           ((f1.z > 0.5f) << 6) | ((f1.w > 0.5f) << 7);
  int v1 = by | (__shfl_xor(by, 1) << 8);
  int v2 = v1 | (__shfl_xor(v1, 2) << 16);
  if ((t & 3) == 0){
    srow[row] = (unsigned)v2;
    fgbits[((z0 + lz) << 11) | ((y0 + ly) << 3) | (x0 >> 5)] = (unsigned)v2;
  }
  __syncthreads();

  const unsigned m = srow[row];
  const unsigned starts = m & ~(m << 1);           // all run starts of this row
  const unsigned sm = starts & (0xFFu << xb);      // starts within this thread's byte

  // A2: init run-start entries + push to balanced worklist (wave prefix-scan)
  {
    int cnt = __popc(sm);
    int pre = cnt;
    #pragma unroll
    for (int d = 1; d < 64; d <<= 1){
      int v = __shfl_up(pre, d);
      if (lane >= d) pre += v;
    }
    int tot = __shfl(pre, 63);              // wave total (inclusive at lane 63)
    int bw = 0;
    if (lane == 63) bw = atomicAdd(&qn, tot);
    bw = __shfl(bw, 63);
    int pos = bw + pre - cnt;               // exclusive offset
    unsigned w = sm;
    while (w){
      int s = __builtin_ctz(w); w &= w - 1;
      int v = (row << 5) | s;
      sl[v] = v;
      q[pos++] = v;
    }
  }
  __syncthreads();
  const int NQ = qn;

  // A3: run-granular unions over the balanced worklist
  const int rel[4][2] = {{-1,-1},{-1,0},{-1,1},{0,-1}};   // (dz,dy)
  for (int it = t; it < NQ; it += 1024){
    int v = q[it];
    int vrow = v >> 5, x = v & 31;
    unsigned mr = srow[vrow];
    unsigned zs = (~mr) >> x;
    int len = zs ? __builtin_ctz(zs) : (32 - x);
    int end = x + len - 1;
    unsigned long long wmask = ((1ull << (end + 2)) - 1) &
                               ~((x == 0) ? 0ull : ((1ull << (x - 1)) - 1));
    int vlz = vrow >> 5, vly = vrow & 31;
    #pragma unroll
    for (int r = 0; r < 4; r++){
      int zz = vlz + rel[r][0], yy = vly + rel[r][1];
      if (zz < 0 || yy < 0 || yy >= TY) continue;
      int nrow = (zz << 5) | yy;
      unsigned mN = srow[nrow];
      unsigned wm = mN & (unsigned)wmask;
      while (wm){
        int bb = __builtin_ctz(wm);
        int ns = run_start(mN, bb);
        uunion(sl, v, (nrow << 5) | ns);
        unsigned t2 = (~mN) >> bb;
        int l2 = t2 ? __builtin_ctz(t2) : (32 - bb);
        unsigned long long clr = (bb + l2 >= 32) ? 0xffffffffull : ((1ull << (bb + l2)) - 1);
        wm &= ~(unsigned)clr;
      }
    }
  }
  __syncthreads();

  // A3.5: flatten run starts (read-only find; one final write per run start)
  for (int it = t; it < NQ; it += 1024){
    int v = q[it];
    sl[v] = ufind_ro(sl, v);
  }
  __syncthreads();

  // A4: per-run label read + translate (once per run), fill 8 voxels, int4 store
  int lab[8];
  int cur = -1;
  #pragma unroll
  for (int k = 0; k < 8; k++){
    int x = xb + k;
    if (!((m >> x) & 1)){ lab[k] = -1; cur = -1; continue; }
    if (cur < 0){
      int rs = (k == 0) ? run_start(m, x) : x;     // k>0 & prev clear -> x is a start
      int r = sl[(row << 5) | rs];
      cur = ((z0 + (r >> 10)) << 16) | ((y0 + ((r >> 5) & 31)) << 8) | (x0 + (r & 31));
    }
    lab[k] = cur;
  }
  *(int4*)(parent + gi0)     = make_int4(lab[0], lab[1], lab[2], lab[3]);
  *(int4*)(parent + gi0 + 4) = make_int4(lab[4], lab[5], lab[6], lab[7]);
}

// ---------------- phase B: face pass — row-run pair enumeration + inline union ----------------
__device__ __forceinline__ void phash_union(unsigned long long* H, unsigned long long key,
                                            int* parent){
  unsigned h = (unsigned)((key * 0x9E3779B97F4A7C15ull) >> 47);   // [0, 2^17)
  while (true){
    unsigned long long old = atomicCAS(&H[h], ~0ULL, key);
    if (old == ~0ULL){ uunion(parent, (int)(key >> 32), (int)(key & 0xffffffffu)); return; }
    if (old == key) return;
    h = (h + 1) & (PHS - 1);
  }
}

__global__ __launch_bounds__(256) void k_pairs(int* __restrict__ parent,
                                               const unsigned* __restrict__ fgbits,
                                               unsigned long long* __restrict__ ph){
  __shared__ unsigned long long pk[256];    // per-block pair-dedup hash
  const int t = threadIdx.x;
  pk[t] = ~0ULL;
  __syncthreads();

  // XCD-chunked bijective swizzle (3584 % 8 == 0): co-resident blocks on one
  // XCD share ~1 MiB of parent (2 z-planes) -> random loads become L2 hits.
  const int nb = (int)gridDim.x;            // 3584
  const int bsw = (blockIdx.x & 7) * (nb >> 3) + (blockIdx.x >> 3);
  const int id = bsw * 256 + t;
  int z, y, x, ot;
  if (id < CA){ ot = 0; z = ((id >> 16) + 1) << 3; y = (id >> 8) & 255; x = id & 255; }
  else {
    int q = id - CA;
    int f = q >> 14;            // 0..27
    int r = q & 16383;
    int g = f / 7, mm = f % 7;
    if      (g == 0){ ot = 1; y = (mm + 1) << 5;  z = r >> 8; x = r & 255; }
    else if (g == 1){ ot = 2; y = (mm << 5) + 31; z = r >> 8; x = r & 255; }
    else if (g == 2){ ot = 3; x = (mm + 1) << 5;  z = r >> 8; y = r & 255; }
    else            { ot = 4; x = (mm << 5) + 31; z = r >> 8; y = r & 255; }
  }
  const int s = x >> 5, xl = x & 31;
  const unsigned wself = fgbits[(z << 11) | (y << 3) | s];
  if ((wself >> xl) & 1){
    const int a = parent[(z << 16) | (y << 8) | x];
    unsigned long long lastkey = ~0ULL;

    auto do_pair = [&](int zz, int yy, int xc){
      int bl = parent[(zz << 16) | (yy << 8) | xc];
      int hi = a > bl ? a : bl, lo = a > bl ? bl : a;
      unsigned long long key = ((unsigned long long)(unsigned)hi << 32) | (unsigned)lo;
      if (key == lastkey) return;
      lastkey = key;
      unsigned h = (unsigned)((key * 0x9E3779B97F4A7C15ull) >> 56);  // [0,256)
      for (int probe = 0; probe < 256; probe++){
        unsigned long long old = atomicCAS(&pk[h], ~0ULL, key);
        if (old == ~0ULL || old == key) return;
        h = (h + 1) & 255;
      }
      phash_union(ph, key, parent);          // LDS hash full -> global
    };

    // row relation: dx in {-1,0,1} vs one fg word; center set => x+-1 same run
    auto do_row = [&](int zz, int yy){
      if (zz < 0 || yy < 0 || yy >= HH) return;
      unsigned mN = fgbits[(zz << 11) | (yy << 3) | s];
      if ((mN >> xl) & 1){ do_pair(zz, yy, x); return; }
      bool l = (xl > 0) ? ((mN >> (xl - 1)) & 1)
                        : (x > 0 && ((fgbits[(zz << 11) | (yy << 3) | (s - 1)] >> 31) & 1));
      bool r = (xl < 31) ? ((mN >> (xl + 1)) & 1)
                         : (x < WW - 1 && (fgbits[(zz << 11) | (yy << 3) | (s + 1)] & 1));
      if (l) do_pair(zz, yy, x - 1);
      if (r) do_pair(zz, yy, x + 1);
    };

    auto do_bit = [&](int zz, int yy, int xc){   // single-voxel check (x-face types)
      if (zz < 0 || yy < 0 || yy >= HH) return;
      unsigned mN = fgbits[(zz << 11) | (yy << 3) | (xc >> 5)];
      if ((mN >> (xc & 31)) & 1) do_pair(zz, yy, xc);
    };

    switch (ot){
      case 0: do_row(z-1, y-1); do_row(z-1, y); do_row(z-1, y+1); break;
      case 1: do_row(z-1, y-1); do_row(z, y-1); break;
      case 2: do_row(z-1, y+1); break;
      case 3: do_bit(z-1, y-1, x-1); do_bit(z-1, y, x-1); do_bit(z-1, y+1, x-1);
              do_bit(z,   y-1, x-1); do_bit(z,   y, x-1); break;
      case 4: do_bit(z-1, y-1, x+1); do_bit(z-1, y, x+1); do_bit(z-1, y+1, x+1);
              do_bit(z,   y-1, x+1); break;
    }
  }
  __syncthreads();
  if (pk[t] != ~0ULL) phash_union(ph, pk[t], parent);
}

// ---------------- phase C: BARRIER-LIGHT boundary + stats ----------------
// 256-thr block = one y-row; each wave independently computes its 64-voxel
// segment's 18-neighborhood erosion IN REGISTERS via shfl (no LDS staging,
// no idle-wave phases). fgbits (512 KiB) is L2/L3-resident.
__device__ __forceinline__ void ghash_add(int* hkey, int* harea, int* hper,
                                          int key, int a, int p){
  unsigned h = ((unsigned)key * 2654435761u) >> 21;   // [0,2048)
  while (true){
    int old = atomicCAS(&hkey[h], -1, key);
    if (old == -1 || old == key){
      atomicAdd(&harea[h], a);
      if (p) atomicAdd(&hper[h], p);
      return;
    }
    h = (h + 1) & (GHS - 1);
  }
}

__global__ __launch_bounds__(256) void k_stats(const int* __restrict__ parent,
                                               const unsigned* __restrict__ fgbits,
                                               int* __restrict__ hkey,
                                               int* __restrict__ harea,
                                               int* __restrict__ hper){
  __shared__ int dk[256], da[256], dp[256];   // tile-root dedup + accumulated stats
  const int t = threadIdx.x;
  const int b = blockIdx.x;                   // 16384 blocks: b = (z<<8)|y
  const int z = b >> 8, y = b & 255;
  const int lane = t & 63;
  const int wv = t >> 6;                      // wave 0..3; covers x in [wv*64, wv*64+64)
  const int c = (b & (NCOPY - 1)) * GHS;      // replicated-hash copy for this block

  dk[t] = -1; da[t] = 0; dp[t] = 0;
  __syncthreads();

  // halo load: lane l<36 loads word (p,q,d): zz=refl(z+p-1), yy=refl(y+q-1),
  // ss = wv*2-1+d  (d in 0..3; out-of-range -> 0, never consumed)
  unsigned wl = 0;
  if (lane < 36){
    int p = lane / 12, q = (lane / 4) % 3, d = lane & 3;
    int ss = wv * 2 - 1 + d;
    if (ss >= 0 && ss < 8){
      int zz = refl(z + p - 1, DD), yy = refl(y + q - 1, HH);
      wl = fgbits[(zz << 11) | (yy << 3) | ss];
    }
  }

  // per-lane erosion word for its own 32-bit word: j=lane>>5, s = wv*2+j
  const int j  = lane >> 5;
  const int s  = wv * 2 + j;
  const int xl = lane & 31;
  auto SW = [&](int p, int q, int dd){ return (unsigned)__shfl((int)wl, p * 12 + q * 4 + j + 1 + dd, 64); };
  auto W  = [&](int p, int q){ return SW(p, q, 0); };
  auto WLf = [&](int p, int q){
    unsigned w = W(p, q);
    unsigned cc = (s > 0) ? ((SW(p, q, -1) >> 31) & 1u) : ((w >> 1) & 1u);
    return (w << 1) | cc;
  };
  auto WRf = [&](int p, int q){
    unsigned w = W(p, q);
    unsigned cc = (s < 7) ? ((SW(p, q, +1) & 1u) << 31) : ((w & 0x40000000u) << 1);
    return (w >> 1) | cc;
  };
  unsigned own = W(1, 1);
  unsigned e = W(0, 0) & W(0, 2) & W(2, 0) & W(2, 2);     // (±1,±1,0)
  e &= W(0, 1) & WLf(0, 1) & WRf(0, 1);                   // (-1,0,*)
  e &= W(2, 1) & WLf(2, 1) & WRf(2, 1);                   // (+1,0,*)
  e &= W(1, 0) & WLf(1, 0) & WRf(1, 0);                   // (0,-1,*)
  e &= W(1, 2) & WLf(1, 2) & WRf(1, 2);                   // (0,+1,*)
  e &= WLf(1, 1) & WRf(1, 1);                             // (0,0,±1)
  const unsigned bndw = own & ~e;

  const int i = b * 256 + t;
  int lab = parent[i];                     // tile-root label; -1 = bg
  int bnd = (lab >= 0) ? (int)((bndw >> xl) & 1) : 0;

  // wave reduce-by-key over TILE roots; leaders insert into block dedup hash
  unsigned long long fgm = __ballot(lab >= 0);
  unsigned long long bm  = __ballot(bnd != 0);
  unsigned long long act = fgm;
  while (act){
    int leader = (int)__ffsll(act) - 1;
    int llab = __shfl(lab, leader);
    unsigned long long match = __ballot(lab == llab) & fgm;
    if (lane == leader){
      int a = (int)__popcll(match);
      int p = (int)__popcll(match & bm);
      unsigned h = ((unsigned)llab * 2654435761u) >> 24;
      bool done = false;
      for (int probe = 0; probe < 256; probe++){
        int old = atomicCAS(&dk[h], -1, llab);
        if (old == -1 || old == llab){
          atomicAdd(&da[h], a);
          if (p) atomicAdd(&dp[h], p);
          done = true; break;
        }
        h = (h + 1) & 255;
      }
      if (!done){                          // dedup hash full (pathological): chase inline
        int l2 = llab, pr = parent[l2];
        while (pr != l2){ l2 = pr; pr = parent[l2]; }
        ghash_add(hkey + c, harea + c, hper + c, l2, a, p);
      }
    }
    act &= ~match;
  }
  __syncthreads();
  // parallel read-only chase of distinct tile-roots, flush to replicated hash
  if (dk[t] >= 0){
    int l2 = dk[t];
    int pr = parent[l2];
    while (pr != l2){ l2 = pr; pr = parent[l2]; }
    ghash_add(hkey + c, harea + c, hper + c, l2, da[t], dp[t]);
  }
}

// ---------------- phase D: PARALLEL merge of copies 1..15 into copy 0 ----------------
__global__ __launch_bounds__(256) void k_merge(int* __restrict__ hkey,
                                               int* __restrict__ harea,
                                               int* __restrict__ hper){
  const int j = GHS + blockIdx.x * 256 + threadIdx.x;   // grid covers (NCOPY-1)*GHS
  int key = hkey[j];
  if (key >= 0) ghash_add(hkey, harea, hper, key, harea[j], hper[j]);
}

// ---------------- phase E: scan copy 0 + finalize ----------------
__global__ __launch_bounds__(256) void k_fin(const int* __restrict__ hkey,
                                             const int* __restrict__ harea,
                                             const int* __restrict__ hper,
                                             float* __restrict__ out){
  __shared__ float ssum[256];
  const int t = threadIdx.x;
  float s = 0.0f;
  for (int j = t; j < GHS; j += 256){
    if (hkey[j] >= 0){
      float a = (float)harea[j];
      float p = (float)hper[j];
      s += 12.566370614359172f * a / (p * p + 1e-5f);
    }
  }
  ssum[t] = s;
  __syncthreads();
  for (int w = 128; w > 0; w >>= 1){
    if (t < w) ssum[t] += ssum[t + w];
    __syncthreads();
  }
  if (t == 0){
    float comp = ssum[0] / 64.0f;
    out[0] = 1.0f / (comp + 1e-5f);
  }
}

// ---------------- launcher ----------------
extern "C" void kernel_launch(void* const* d_in, const int* in_sizes, int n_in,
                              void* d_out, int out_size, void* d_ws, size_t ws_size,
                              hipStream_t stream){
  const float* y = (const float*)d_in[0];
  char* w = (char*)d_ws;
  int* parent            = (int*)w;                    w += (size_t)NN * 4;          // 16 MiB
  unsigned long long* ph = (unsigned long long*)w;     w += (size_t)PHS * 8;         // 1 MiB
  int* hkey              = (int*)w;                    w += (size_t)NCOPY * GHS * 4; // 128 KiB
  int* harea             = (int*)w;                    w += (size_t)NCOPY * GHS * 4;
  int* hper              = (int*)w;                    w += (size_t)NCOPY * GHS * 4;
  unsigned* fgbits       = (unsigned*)w;               w += (size_t)NSEG * 4;        // 512 KiB
  float* out = (float*)d_out;

  hipLaunchKernelGGL(k_local, dim3(512),       dim3(1024), 0, stream, y, parent, fgbits, hkey, harea, hper, ph);
  hipLaunchKernelGGL(k_pairs, dim3(CFACE/256), dim3(256),  0, stream, parent, fgbits, ph);
  hipLaunchKernelGGL(k_stats, dim3(NN/256),    dim3(256),  0, stream, parent, fgbits, hkey, harea, hper);
  hipLaunchKernelGGL(k_merge, dim3((NCOPY-1)*GHS/256), dim3(256), 0, stream, hkey, harea, hper);
  hipLaunchKernelGGL(k_fin,   dim3(1),         dim3(256),  0, stream, hkey, harea, hper, out);
}

// Round 21
// 156.996 us; speedup vs baseline: 1.5468x; 1.5468x over previous
//
#include <hip/hip_runtime.h>

#define DD 64
#define HH 256
#define WW 256
#define NN (DD*HH*WW)   // 4194304
#define GHS 2048        // stats-hash slots per copy (power of 2; >= 2x ref L_MAX)
#define NCOPY 16        // replicated stats hashes (contention spread)
#define PHS 131072      // global pair-hash slots (power of 2, 64-bit keys)
#define NSEG (NN/32)    // 131072 bitmask words

// tile for local CCL phase
#define TZ 8
#define TY 32
#define TX 32
#define TVOX (TZ*TY*TX) // 8192 -> 32 KB LDS

// face-voxel enumeration for cross-tile pass
#define CA 458752            // 7 * 65536   (z-faces)
#define CB 114688            // 7 * 16384   (each of y0/y31/x0/x31 faces)
#define CFACE (CA + 4*CB)    // 917504 = 3584 * 256

// ---------------- union-find (works on LDS or global) ----------------
// Safety: every write stores an ancestor and preserves P[x] <= x; 4B accesses
// are HW-atomic, so concurrent halving stores cannot lose connectivity.
__device__ __forceinline__ int ufind(int* P, int x){
  int p = P[x];
  while (p != x){
    int gp = P[p];
    if (gp != p) P[x] = gp;   // path halving
    x = gp;
    p = P[x];
  }
  return x;
}

__device__ __forceinline__ int ufind_ro(const int* P, int x){
  int p = P[x];
  while (p != x){ x = p; p = P[x]; }
  return x;
}

__device__ __forceinline__ void uunion(int* P, int a, int b){
  while (true){
    a = ufind(P, a);
    b = ufind(P, b);
    if (a == b) return;
    if (a < b){ int t = a; a = b; b = t; }   // link big -> small
    int old = atomicMin(&P[a], b);
    if (old == a) return;
    a = old;
  }
}

// run start of bit x in mask m (bit x must be set)
__device__ __forceinline__ int run_start(unsigned m, int x){
  unsigned zb = (~m) & ((x == 0) ? 0u : ((1u << x) - 1u));
  return (zb == 0) ? 0 : (32 - __builtin_clz(zb));
}

__device__ __forceinline__ int refl(int v, int L){ return v < 0 ? 1 : (v >= L ? L - 2 : v); }

// ---------------- phase A: run-granular tile-local CCL, worklist-balanced ----------------
__global__ __launch_bounds__(1024) void k_local(const float* __restrict__ in,
                                                int* __restrict__ parent,
                                                unsigned* __restrict__ fgbits,
                                                int* __restrict__ hkey,
                                                int* __restrict__ harea,
                                                int* __restrict__ hper,
                                                unsigned long long* __restrict__ ph){
  __shared__ int sl[TVOX];                // union-find nodes: run-start entries only
  __shared__ unsigned srow[256];          // fg mask per (lz,ly) row
  __shared__ int q[4096];                 // run-start worklist (max 16 runs/row * 256)
  __shared__ int qn;
  const int t = threadIdx.x;
  const int lane = t & 63;
  const int b = blockIdx.x;               // 512 tiles: 8 x 8 x 8
  const int z0 = (b >> 6) * TZ;
  const int y0 = ((b >> 3) & 7) * TY;
  const int x0 = (b & 7) * TX;

  // init NCOPY stats-hash copies (16*2048 = 32768 = 32 blocks x 1024)
  if (b < (NCOPY * GHS) / 1024){ int j = b * 1024 + t; hkey[j] = -1; harea[j] = 0; hper[j] = 0; }
  { int j = b * 1024 + t; if (j < PHS) ph[j] = ~0ULL; }   // pair hash sentinel
  if (t == 0) qn = 0;

  // blocked mapping: thread t owns one byte (8 voxels) of row (t>>2)
  const int row = t >> 2;                 // (lz<<5)|ly
  const int xb  = (t & 3) * 8;
  const int lz  = row >> 5, ly = row & 31;
  const int gi0 = ((z0 + lz) << 16) | ((y0 + ly) << 8) | (x0 + xb);

  // A1: vectorized load -> fg byte -> row mask via 2 shuffle rounds
  float4 f0 = *(const float4*)(in + gi0);
  float4 f1 = *(const float4*)(in + gi0 + 4);
  int by = (f0.x > 0.5f)        | ((f0.y > 0.5f) << 1) |
           ((f0.z > 0.5f) << 2) | ((f0.w > 0.5f) << 3) |
           ((f1.x > 0.5f) << 4) | ((f1.y > 0.5f) << 5) |
           ((f1.z > 0.5f) << 6) | ((f1.w > 0.5f) << 7);
  int v1 = by | (__shfl_xor(by, 1) << 8);
  int v2 = v1 | (__shfl_xor(v1, 2) << 16);
  if ((t & 3) == 0){
    srow[row] = (unsigned)v2;
    fgbits[((z0 + lz) << 11) | ((y0 + ly) << 3) | (x0 >> 5)] = (unsigned)v2;
  }
  __syncthreads();

  const unsigned m = srow[row];
  const unsigned starts = m & ~(m << 1);           // all run starts of this row
  const unsigned sm = starts & (0xFFu << xb);      // starts within this thread's byte

  // A2: init run-start entries + push to balanced worklist (wave prefix-scan)
  {
    int cnt = __popc(sm);
    int pre = cnt;
    #pragma unroll
    for (int d = 1; d < 64; d <<= 1){
      int v = __shfl_up(pre, d);
      if (lane >= d) pre += v;
    }
    int tot = __shfl(pre, 63);              // wave total (inclusive at lane 63)
    int bw = 0;
    if (lane == 63) bw = atomicAdd(&qn, tot);
    bw = __shfl(bw, 63);
    int pos = bw + pre - cnt;               // exclusive offset
    unsigned w = sm;
    while (w){
      int s = __builtin_ctz(w); w &= w - 1;
      int v = (row << 5) | s;
      sl[v] = v;
      q[pos++] = v;
    }
  }
  __syncthreads();
  const int NQ = qn;

  // A3: run-granular unions over the balanced worklist
  const int rel[4][2] = {{-1,-1},{-1,0},{-1,1},{0,-1}};   // (dz,dy)
  for (int it = t; it < NQ; it += 1024){
    int v = q[it];
    int vrow = v >> 5, x = v & 31;
    unsigned mr = srow[vrow];
    unsigned zs = (~mr) >> x;
    int len = zs ? __builtin_ctz(zs) : (32 - x);
    int end = x + len - 1;
    unsigned long long wmask = ((1ull << (end + 2)) - 1) &
                               ~((x == 0) ? 0ull : ((1ull << (x - 1)) - 1));
    int vlz = vrow >> 5, vly = vrow & 31;
    #pragma unroll
    for (int r = 0; r < 4; r++){
      int zz = vlz + rel[r][0], yy = vly + rel[r][1];
      if (zz < 0 || yy < 0 || yy >= TY) continue;
      int nrow = (zz << 5) | yy;
      unsigned mN = srow[nrow];
      unsigned wm = mN & (unsigned)wmask;
      while (wm){
        int bb = __builtin_ctz(wm);
        int ns = run_start(mN, bb);
        uunion(sl, v, (nrow << 5) | ns);
        unsigned t2 = (~mN) >> bb;
        int l2 = t2 ? __builtin_ctz(t2) : (32 - bb);
        unsigned long long clr = (bb + l2 >= 32) ? 0xffffffffull : ((1ull << (bb + l2)) - 1);
        wm &= ~(unsigned)clr;
      }
    }
  }
  __syncthreads();

  // A3.5: flatten run starts (read-only find; one final write per run start)
  for (int it = t; it < NQ; it += 1024){
    int v = q[it];
    sl[v] = ufind_ro(sl, v);
  }
  __syncthreads();

  // A4: per-run label read + translate (once per run), fill 8 voxels, int4 store
  int lab[8];
  int cur = -1;
  #pragma unroll
  for (int k = 0; k < 8; k++){
    int x = xb + k;
    if (!((m >> x) & 1)){ lab[k] = -1; cur = -1; continue; }
    if (cur < 0){
      int rs = (k == 0) ? run_start(m, x) : x;     // k>0 & prev clear -> x is a start
      int r = sl[(row << 5) | rs];
      cur = ((z0 + (r >> 10)) << 16) | ((y0 + ((r >> 5) & 31)) << 8) | (x0 + (r & 31));
    }
    lab[k] = cur;
  }
  *(int4*)(parent + gi0)     = make_int4(lab[0], lab[1], lab[2], lab[3]);
  *(int4*)(parent + gi0 + 4) = make_int4(lab[4], lab[5], lab[6], lab[7]);
}

// ---------------- phase B: face pass — row-run pair enumeration + inline union ----------------
__device__ __forceinline__ void phash_union(unsigned long long* H, unsigned long long key,
                                            int* parent){
  unsigned h = (unsigned)((key * 0x9E3779B97F4A7C15ull) >> 47);   // [0, 2^17)
  while (true){
    unsigned long long old = atomicCAS(&H[h], ~0ULL, key);
    if (old == ~0ULL){ uunion(parent, (int)(key >> 32), (int)(key & 0xffffffffu)); return; }
    if (old == key) return;
    h = (h + 1) & (PHS - 1);
  }
}

__global__ __launch_bounds__(256) void k_pairs(int* __restrict__ parent,
                                               const unsigned* __restrict__ fgbits,
                                               unsigned long long* __restrict__ ph){
  __shared__ unsigned long long pk[256];    // per-block pair-dedup hash
  const int t = threadIdx.x;
  pk[t] = ~0ULL;
  __syncthreads();

  // XCD-chunked bijective swizzle (3584 % 8 == 0): co-resident blocks on one
  // XCD share ~1 MiB of parent (2 z-planes) -> random loads become L2 hits.
  const int nb = (int)gridDim.x;            // 3584
  const int bsw = (blockIdx.x & 7) * (nb >> 3) + (blockIdx.x >> 3);
  const int id = bsw * 256 + t;
  int z, y, x, ot;
  if (id < CA){ ot = 0; z = ((id >> 16) + 1) << 3; y = (id >> 8) & 255; x = id & 255; }
  else {
    int q = id - CA;
    int f = q >> 14;            // 0..27
    int r = q & 16383;
    int g = f / 7, mm = f % 7;
    if      (g == 0){ ot = 1; y = (mm + 1) << 5;  z = r >> 8; x = r & 255; }
    else if (g == 1){ ot = 2; y = (mm << 5) + 31; z = r >> 8; x = r & 255; }
    else if (g == 2){ ot = 3; x = (mm + 1) << 5;  z = r >> 8; y = r & 255; }
    else            { ot = 4; x = (mm << 5) + 31; z = r >> 8; y = r & 255; }
  }
  const int s = x >> 5, xl = x & 31;
  const unsigned wself = fgbits[(z << 11) | (y << 3) | s];
  if ((wself >> xl) & 1){
    const int a = parent[(z << 16) | (y << 8) | x];
    unsigned long long lastkey = ~0ULL;

    auto do_pair = [&](int zz, int yy, int xc){
      int bl = parent[(zz << 16) | (yy << 8) | xc];
      int hi = a > bl ? a : bl, lo = a > bl ? bl : a;
      unsigned long long key = ((unsigned long long)(unsigned)hi << 32) | (unsigned)lo;
      if (key == lastkey) return;
      lastkey = key;
      unsigned h = (unsigned)((key * 0x9E3779B97F4A7C15ull) >> 56);  // [0,256)
      for (int probe = 0; probe < 256; probe++){
        unsigned long long old = atomicCAS(&pk[h], ~0ULL, key);
        if (old == ~0ULL || old == key) return;
        h = (h + 1) & 255;
      }
      phash_union(ph, key, parent);          // LDS hash full -> global
    };

    // row relation: dx in {-1,0,1} vs one fg word; center set => x+-1 same run
    auto do_row = [&](int zz, int yy){
      if (zz < 0 || yy < 0 || yy >= HH) return;
      unsigned mN = fgbits[(zz << 11) | (yy << 3) | s];
      if ((mN >> xl) & 1){ do_pair(zz, yy, x); return; }
      bool l = (xl > 0) ? ((mN >> (xl - 1)) & 1)
                        : (x > 0 && ((fgbits[(zz << 11) | (yy << 3) | (s - 1)] >> 31) & 1));
      bool r = (xl < 31) ? ((mN >> (xl + 1)) & 1)
                         : (x < WW - 1 && (fgbits[(zz << 11) | (yy << 3) | (s + 1)] & 1));
      if (l) do_pair(zz, yy, x - 1);
      if (r) do_pair(zz, yy, x + 1);
    };

    auto do_bit = [&](int zz, int yy, int xc){   // single-voxel check (x-face types)
      if (zz < 0 || yy < 0 || yy >= HH) return;
      unsigned mN = fgbits[(zz << 11) | (yy << 3) | (xc >> 5)];
      if ((mN >> (xc & 31)) & 1) do_pair(zz, yy, xc);
    };

    switch (ot){
      case 0: do_row(z-1, y-1); do_row(z-1, y); do_row(z-1, y+1); break;
      case 1: do_row(z-1, y-1); do_row(z, y-1); break;
      case 2: do_row(z-1, y+1); break;
      case 3: do_bit(z-1, y-1, x-1); do_bit(z-1, y, x-1); do_bit(z-1, y+1, x-1);
              do_bit(z,   y-1, x-1); do_bit(z,   y, x-1); break;
      case 4: do_bit(z-1, y-1, x+1); do_bit(z-1, y, x+1); do_bit(z-1, y+1, x+1);
              do_bit(z,   y-1, x+1); break;
    }
  }
  __syncthreads();
  if (pk[t] != ~0ULL) phash_union(ph, pk[t], parent);
}

// ---------------- phase C: stats — register erosion + two-level dedup ----------------
// 1024-thr block = 4 y-rows (4096 blocks). Wave wv: row ry=wv>>2, x-quarter
// qx=wv&3. Erosion in registers via shfl (no LDS staging phases). Flush path:
// tile-root LDS dedup -> parallel chase -> FINAL-root LDS dedup -> ~2-6 global
// flushes per block (round-20 showed flush-count x same-key CAS contention is
// the k_stats cost: 131K flushes = 129us, 12-20K = <42us).
__device__ __forceinline__ void ghash_add(int* hkey, int* harea, int* hper,
                                          int key, int a, int p){
  unsigned h = ((unsigned)key * 2654435761u) >> 21;   // [0,2048)
  while (true){
    int old = atomicCAS(&hkey[h], -1, key);
    if (old == -1 || old == key){
      atomicAdd(&harea[h], a);
      if (p) atomicAdd(&hper[h], p);
      return;
    }
    h = (h + 1) & (GHS - 1);
  }
}

__global__ __launch_bounds__(1024) void k_stats(const int* __restrict__ parent,
                                                const unsigned* __restrict__ fgbits,
                                                int* __restrict__ hkey,
                                                int* __restrict__ harea,
                                                int* __restrict__ hper){
  __shared__ int dk[256], da[256], dp[256];   // tile-root dedup + stats
  __shared__ int fk[256], fa[256], fp[256];   // FINAL-root dedup + stats
  const int t = threadIdx.x;
  const int b = blockIdx.x;                   // 4096 blocks: z = b>>6, y0 = (b&63)*4
  const int z = b >> 6;
  const int y0 = (b & 63) * 4;
  const int lane = t & 63;
  const int wv = t >> 6;                      // 0..15
  const int ry = wv >> 2;                     // row in block (0..3)
  const int qx = wv & 3;                      // x-quarter: x in [qx*64, qx*64+64)
  const int y  = y0 + ry;
  const int c = (b & (NCOPY - 1)) * GHS;      // replicated-hash copy for this block

  if (t < 256){ dk[t] = -1; da[t] = 0; dp[t] = 0; fk[t] = -1; fa[t] = 0; fp[t] = 0; }
  __syncthreads();

  // halo load: lane l<36 loads word (p,qy,d): ss = qx*2-1+d (d in 0..3)
  unsigned wl = 0;
  if (lane < 36){
    int p = lane / 12, qy = (lane / 4) % 3, d = lane & 3;
    int ss = qx * 2 - 1 + d;
    if (ss >= 0 && ss < 8){
      int zz = refl(z + p - 1, DD), yy = refl(y + qy - 1, HH);
      wl = fgbits[(zz << 11) | (yy << 3) | ss];
    }
  }

  // per-lane erosion for its own 32-bit word: j=lane>>5, s = qx*2+j
  const int j  = lane >> 5;
  const int s  = qx * 2 + j;
  const int xl = lane & 31;
  auto SW = [&](int p, int qy, int dd){ return (unsigned)__shfl((int)wl, p * 12 + qy * 4 + j + 1 + dd, 64); };
  auto W  = [&](int p, int qy){ return SW(p, qy, 0); };
  auto WLf = [&](int p, int qy){
    unsigned w = W(p, qy);
    unsigned cc = (s > 0) ? ((SW(p, qy, -1) >> 31) & 1u) : ((w >> 1) & 1u);
    return (w << 1) | cc;
  };
  auto WRf = [&](int p, int qy){
    unsigned w = W(p, qy);
    unsigned cc = (s < 7) ? ((SW(p, qy, +1) & 1u) << 31) : ((w & 0x40000000u) << 1);
    return (w >> 1) | cc;
  };
  unsigned own = W(1, 1);
  unsigned e = W(0, 0) & W(0, 2) & W(2, 0) & W(2, 2);     // (±1,±1,0)
  e &= W(0, 1) & WLf(0, 1) & WRf(0, 1);                   // (-1,0,*)
  e &= W(2, 1) & WLf(2, 1) & WRf(2, 1);                   // (+1,0,*)
  e &= W(1, 0) & WLf(1, 0) & WRf(1, 0);                   // (0,-1,*)
  e &= W(1, 2) & WLf(1, 2) & WRf(1, 2);                   // (0,+1,*)
  e &= WLf(1, 1) & WRf(1, 1);                             // (0,0,±1)
  const unsigned bndw = own & ~e;

  const int i = b * 1024 + t;
  int lab = parent[i];                     // tile-root label; -1 = bg
  int bnd = (lab >= 0) ? (int)((bndw >> xl) & 1) : 0;

  // wave reduce-by-key over TILE roots; leaders insert into block dedup hash
  unsigned long long fgm = __ballot(lab >= 0);
  unsigned long long bm  = __ballot(bnd != 0);
  unsigned long long act = fgm;
  while (act){
    int leader = (int)__ffsll(act) - 1;
    int llab = __shfl(lab, leader);
    unsigned long long match = __ballot(lab == llab) & fgm;
    if (lane == leader){
      int a = (int)__popcll(match);
      int p = (int)__popcll(match & bm);
      unsigned h = ((unsigned)llab * 2654435761u) >> 24;
      bool done = false;
      for (int probe = 0; probe < 256; probe++){
        int old = atomicCAS(&dk[h], -1, llab);
        if (old == -1 || old == llab){
          atomicAdd(&da[h], a);
          if (p) atomicAdd(&dp[h], p);
          done = true; break;
        }
        h = (h + 1) & 255;
      }
      if (!done){                          // dedup hash full (pathological): chase inline
        int l2 = llab, pr = parent[l2];
        while (pr != l2){ l2 = pr; pr = parent[l2]; }
        ghash_add(hkey + c, harea + c, hper + c, l2, a, p);
      }
    }
    act &= ~match;
  }
  __syncthreads();
  // parallel chase of distinct tile-roots -> second dedup keyed by FINAL root
  if (t < 256 && dk[t] >= 0){
    int l2 = dk[t];
    int pr = parent[l2];
    while (pr != l2){ l2 = pr; pr = parent[l2]; }
    unsigned h = ((unsigned)l2 * 2654435761u) >> 24;
    bool done = false;
    for (int probe = 0; probe < 256; probe++){
      int old = atomicCAS(&fk[h], -1, l2);
      if (old == -1 || old == l2){
        atomicAdd(&fa[h], da[t]);
        if (dp[t]) atomicAdd(&fp[h], dp[t]);
        done = true; break;
      }
      h = (h + 1) & 255;
    }
    if (!done) ghash_add(hkey + c, harea + c, hper + c, l2, da[t], dp[t]);
  }
  __syncthreads();
  // flush ~2-6 distinct FINAL roots to this block's replicated global hash
  if (t < 256 && fk[t] >= 0) ghash_add(hkey + c, harea + c, hper + c, fk[t], fa[t], fp[t]);
}

// ---------------- phase D: PARALLEL merge of copies 1..15 into copy 0 ----------------
__global__ __launch_bounds__(256) void k_merge(int* __restrict__ hkey,
                                               int* __restrict__ harea,
                                               int* __restrict__ hper){
  const int j = GHS + blockIdx.x * 256 + threadIdx.x;   // grid covers (NCOPY-1)*GHS
  int key = hkey[j];
  if (key >= 0) ghash_add(hkey, harea, hper, key, harea[j], hper[j]);
}

// ---------------- phase E: scan copy 0 + finalize ----------------
__global__ __launch_bounds__(256) void k_fin(const int* __restrict__ hkey,
                                             const int* __restrict__ harea,
                                             const int* __restrict__ hper,
                                             float* __restrict__ out){
  __shared__ float ssum[256];
  const int t = threadIdx.x;
  float s = 0.0f;
  for (int j = t; j < GHS; j += 256){
    if (hkey[j] >= 0){
      float a = (float)harea[j];
      float p = (float)hper[j];
      s += 12.566370614359172f * a / (p * p + 1e-5f);
    }
  }
  ssum[t] = s;
  __syncthreads();
  for (int w = 128; w > 0; w >>= 1){
    if (t < w) ssum[t] += ssum[t + w];
    __syncthreads();
  }
  if (t == 0){
    float comp = ssum[0] / 64.0f;
    out[0] = 1.0f / (comp + 1e-5f);
  }
}

// ---------------- launcher ----------------
extern "C" void kernel_launch(void* const* d_in, const int* in_sizes, int n_in,
                              void* d_out, int out_size, void* d_ws, size_t ws_size,
                              hipStream_t stream){
  const float* y = (const float*)d_in[0];
  char* w = (char*)d_ws;
  int* parent            = (int*)w;                    w += (size_t)NN * 4;          // 16 MiB
  unsigned long long* ph = (unsigned long long*)w;     w += (size_t)PHS * 8;         // 1 MiB
  int* hkey              = (int*)w;                    w += (size_t)NCOPY * GHS * 4; // 128 KiB
  int* harea             = (int*)w;                    w += (size_t)NCOPY * GHS * 4;
  int* hper              = (int*)w;                    w += (size_t)NCOPY * GHS * 4;
  unsigned* fgbits       = (unsigned*)w;               w += (size_t)NSEG * 4;        // 512 KiB
  float* out = (float*)d_out;

  hipLaunchKernelGGL(k_local, dim3(512),       dim3(1024), 0, stream, y, parent, fgbits, hkey, harea, hper, ph);
  hipLaunchKernelGGL(k_pairs, dim3(CFACE/256), dim3(256),  0, stream, parent, fgbits, ph);
  hipLaunchKernelGGL(k_stats, dim3(NN/1024),   dim3(1024), 0, stream, parent, fgbits, hkey, harea, hper);
  hipLaunchKernelGGL(k_merge, dim3((NCOPY-1)*GHS/256), dim3(256), 0, stream, hkey, harea, hper);
  hipLaunchKernelGGL(k_fin,   dim3(1),         dim3(256),  0, stream, hkey, harea, hper, out);
}